// Round 1
// baseline (1918.942 us; speedup 1.0000x reference)
//
#include <hip/hip_runtime.h>
#include <hip/hip_bf16.h>

#define NFEAT 128
#define NHID  64
#define NCLASS 40
#define NLAYERS 4

// ---------------- CSR build ----------------

__global__ void count_edges_k(const int* __restrict__ ei, int E,
                              int* __restrict__ cnt_row, int* __restrict__ cnt_col) {
    int e = blockIdx.x * blockDim.x + threadIdx.x;
    if (e >= E) return;
    atomicAdd(&cnt_row[ei[e]], 1);      // row = ei[0][e]
    atomicAdd(&cnt_col[ei[E + e]], 1);  // col = ei[1][e]
}

__global__ void dinv_k(const int* __restrict__ cnt_col, float* __restrict__ dinv, int n) {
    int v = blockIdx.x * blockDim.x + threadIdx.x;
    if (v >= n) return;
    // deg includes the self loop
    dinv[v] = 1.0f / sqrtf((float)(cnt_col[v] + 1));
}

// block-level exclusive scan (1024 elems / block), emits block sums
__global__ void scanA_k(const int* __restrict__ cnt, int* __restrict__ off,
                        int* __restrict__ bsum, int n) {
    __shared__ int t[1024];
    int i = blockIdx.x * 1024 + threadIdx.x;
    int x = (i < n) ? cnt[i] : 0;
    t[threadIdx.x] = x;
    __syncthreads();
    for (int d = 1; d < 1024; d <<= 1) {
        int y = (threadIdx.x >= (unsigned)d) ? t[threadIdx.x - d] : 0;
        __syncthreads();
        t[threadIdx.x] += y;
        __syncthreads();
    }
    if (i < n) off[i] = t[threadIdx.x] - x;   // exclusive
    if (threadIdx.x == 1023) bsum[blockIdx.x] = t[1023];
}

// single-block exclusive scan of block sums (nb <= 1024)
__global__ void scanB_k(int* __restrict__ bsum, int nb) {
    __shared__ int t[1024];
    int x = (threadIdx.x < (unsigned)nb) ? bsum[threadIdx.x] : 0;
    t[threadIdx.x] = x;
    __syncthreads();
    for (int d = 1; d < 1024; d <<= 1) {
        int y = (threadIdx.x >= (unsigned)d) ? t[threadIdx.x - d] : 0;
        __syncthreads();
        t[threadIdx.x] += y;
        __syncthreads();
    }
    if (threadIdx.x < (unsigned)nb) bsum[threadIdx.x] = t[threadIdx.x] - x; // exclusive
}

__global__ void scanC_k(int* __restrict__ off, const int* __restrict__ bsum,
                        int* __restrict__ cur, int n, int total) {
    int i = blockIdx.x * 1024 + threadIdx.x;
    if (i < n) {
        int o = off[i] + bsum[blockIdx.x];
        off[i] = o;
        cur[i] = o;
    }
    if (i == 0) off[n] = total;
}

__global__ void fill_k(const int* __restrict__ ei, int E, const float* __restrict__ dinv,
                       int* __restrict__ cur_col, int* __restrict__ cur_row,
                       uint2* __restrict__ csr_col, int* __restrict__ csr_row) {
    int e = blockIdx.x * blockDim.x + threadIdx.x;
    if (e >= E) return;
    int r = ei[e];
    int c = ei[E + e];
    int p = atomicAdd(&cur_col[c], 1);
    uint2 ent;
    ent.x = (unsigned)r;
    ent.y = __float_as_uint(dinv[r]);
    csr_col[p] = ent;
    int q = atomicAdd(&cur_row[r], 1);
    csr_row[q] = c;
}

// ---------------- dense (row-major A [n,K] @ W[M,K]^T + b) ----------------

template<int K, int M, bool RELU, bool BIAS>
__global__ void dense_k(const float* __restrict__ A, const float* __restrict__ W,
                        const float* __restrict__ b, float* __restrict__ out, int n) {
    int v = blockIdx.x * blockDim.x + threadIdx.x;
    if (v >= n) return;
    float a[K];
    const float4* ap = reinterpret_cast<const float4*>(A + (size_t)v * K);
#pragma unroll
    for (int k = 0; k < K / 4; ++k) {
        float4 t = ap[k];
        a[4 * k + 0] = t.x; a[4 * k + 1] = t.y; a[4 * k + 2] = t.z; a[4 * k + 3] = t.w;
    }
    float4* op = reinterpret_cast<float4*>(out + (size_t)v * M);
#pragma unroll 1
    for (int m = 0; m < M; m += 4) {
        float acc0 = BIAS ? b[m + 0] : 0.f;
        float acc1 = BIAS ? b[m + 1] : 0.f;
        float acc2 = BIAS ? b[m + 2] : 0.f;
        float acc3 = BIAS ? b[m + 3] : 0.f;
#pragma unroll
        for (int k = 0; k < K; ++k) {
            float av = a[k];
            acc0 = fmaf(av, W[(m + 0) * K + k], acc0);
            acc1 = fmaf(av, W[(m + 1) * K + k], acc1);
            acc2 = fmaf(av, W[(m + 2) * K + k], acc2);
            acc3 = fmaf(av, W[(m + 3) * K + k], acc3);
        }
        if (RELU) {
            acc0 = fmaxf(acc0, 0.f); acc1 = fmaxf(acc1, 0.f);
            acc2 = fmaxf(acc2, 0.f); acc3 = fmaxf(acc3, 0.f);
        }
        float4 o; o.x = acc0; o.y = acc1; o.z = acc2; o.w = acc3;
        op[m >> 2] = o;
    }
}

// ---------------- gamma (G2 gate): wave per node ----------------

__global__ void gamma_k(const float* __restrict__ X, const int* __restrict__ row_off,
                        const int* __restrict__ csr_row, float* __restrict__ g, int n) {
    int v = blockIdx.x * 4 + (threadIdx.x >> 6);
    int lane = threadIdx.x & 63;
    if (v >= n) return;
    float xv = X[v * NHID + lane];
    int beg = row_off[v], end = row_off[v + 1];
    float part = 0.f;
    for (int e = beg; e < end; ++e) {
        int c = csr_row[e];
        float d = xv - X[c * NHID + lane];
        part = fmaf(d, d, part);
    }
#pragma unroll
    for (int o = 32; o > 0; o >>= 1) part += __shfl_xor(part, o, 64);
    if (lane == 0) {
        float cnt = (float)(end - beg);
        g[v] = tanhf(part / fmaxf(cnt, 1.f));
    }
}

// ---------------- aggregation + gated update (in place) ----------------

__global__ void agg_update_k(float* __restrict__ X, const float* __restrict__ H,
                             const float* __restrict__ skip, const float* __restrict__ g,
                             const float* __restrict__ dinv, const float* __restrict__ bias,
                             const int* __restrict__ col_off, const uint2* __restrict__ csr_col,
                             int n) {
    int v = blockIdx.x * 4 + (threadIdx.x >> 6);
    int lane = threadIdx.x & 63;
    if (v >= n) return;
    int beg = col_off[v], end = col_off[v + 1];
    float acc = 0.f;
    for (int e = beg; e < end; ++e) {
        uint2 ent = csr_col[e];
        acc = fmaf(__uint_as_float(ent.y), H[(int)ent.x * NHID + lane], acc);
    }
    float dv = dinv[v];
    int idx = v * NHID + lane;
    float hv = H[idx];
    float pre = fmaf(dv, acc, dv * dv * hv) + bias[lane];
    float xagg = fmaxf(pre, 0.f);
    float gv = g[v];
    float Ainv = 1.0f / (1.0f + 2.0f * gv);
    float Bc = gv * Ainv;
    X[idx] = Ainv * X[idx] + Bc * (xagg + skip[idx]);
}

// ---------------- launch ----------------

extern "C" void kernel_launch(void* const* d_in, const int* in_sizes, int n_in,
                              void* d_out, int out_size, void* d_ws, size_t ws_size,
                              hipStream_t stream) {
    const float* x      = (const float*)d_in[0];
    const int*   ei     = (const int*)  d_in[1];
    const float* enc_W  = (const float*)d_in[2];
    const float* enc_b  = (const float*)d_in[3];
    const float* conv_W = (const float*)d_in[4];
    const float* conv_b = (const float*)d_in[5];
    const float* W_skip = (const float*)d_in[6];
    const float* dec_W  = (const float*)d_in[7];
    const float* dec_b  = (const float*)d_in[8];

    const int n = in_sizes[0] / NFEAT;
    const int E = in_sizes[1] / 2;

    char* ws = (char*)d_ws;
    auto alloc = [&](size_t bytes) {
        char* p = ws;
        ws += (bytes + 255) & ~(size_t)255;
        return p;
    };

    float* X    = (float*)alloc((size_t)n * NHID * 4);
    float* H    = (float*)alloc((size_t)n * NHID * 4);
    float* skip = (float*)alloc((size_t)n * NHID * 4);
    float* g    = (float*)alloc((size_t)n * 4);
    float* dinv = (float*)alloc((size_t)n * 4);
    int* cnt_row = (int*)alloc((size_t)n * 4);
    int* cnt_col = (int*)alloc((size_t)n * 4);
    int* row_off = (int*)alloc((size_t)(n + 1) * 4);
    int* col_off = (int*)alloc((size_t)(n + 1) * 4);
    int* cur_row = (int*)alloc((size_t)n * 4);
    int* cur_col = (int*)alloc((size_t)n * 4);
    int* bsr = (int*)alloc(1024 * 4);
    int* bsc = (int*)alloc(1024 * 4);
    uint2* csr_col = (uint2*)alloc((size_t)E * 8);
    int*   csr_row = (int*)alloc((size_t)E * 4);

    hipMemsetAsync(cnt_row, 0, (size_t)n * 4, stream);
    hipMemsetAsync(cnt_col, 0, (size_t)n * 4, stream);

    count_edges_k<<<(E + 255) / 256, 256, 0, stream>>>(ei, E, cnt_row, cnt_col);
    dinv_k<<<(n + 255) / 256, 256, 0, stream>>>(cnt_col, dinv, n);

    int nb = (n + 1023) / 1024;
    scanA_k<<<nb, 1024, 0, stream>>>(cnt_col, col_off, bsc, n);
    scanA_k<<<nb, 1024, 0, stream>>>(cnt_row, row_off, bsr, n);
    scanB_k<<<1, 1024, 0, stream>>>(bsc, nb);
    scanB_k<<<1, 1024, 0, stream>>>(bsr, nb);
    scanC_k<<<nb, 1024, 0, stream>>>(col_off, bsc, cur_col, n, E);
    scanC_k<<<nb, 1024, 0, stream>>>(row_off, bsr, cur_row, n, E);
    fill_k<<<(E + 255) / 256, 256, 0, stream>>>(ei, E, dinv, cur_col, cur_row, csr_col, csr_row);

    // encoder: X = relu(x @ enc_W^T + enc_b)
    dense_k<NFEAT, NHID, true, true><<<(n + 255) / 256, 256, 0, stream>>>(x, enc_W, enc_b, X, n);
    // skip_val = X_init @ W_skip^T
    dense_k<NHID, NHID, false, false><<<(n + 255) / 256, 256, 0, stream>>>(X, W_skip, nullptr, skip, n);

    for (int l = 0; l < NLAYERS; ++l) {
        gamma_k<<<(n + 3) / 4, 256, 0, stream>>>(X, row_off, csr_row, g, n);
        dense_k<NHID, NHID, false, false><<<(n + 255) / 256, 256, 0, stream>>>(X, conv_W, nullptr, H, n);
        agg_update_k<<<(n + 3) / 4, 256, 0, stream>>>(X, H, skip, g, dinv, conv_b, col_off, csr_col, n);
    }

    // decode: out = X @ dec_W^T + dec_b
    dense_k<NHID, NCLASS, false, true><<<(n + 255) / 256, 256, 0, stream>>>(X, dec_W, dec_b, (float*)d_out, n);
}

// Round 2
// 942.875 us; speedup vs baseline: 2.0352x; 2.0352x over previous
//
#include <hip/hip_runtime.h>
#include <hip/hip_bf16.h>

#define NFEAT 128
#define NHID  64
#define NCLASS 40
#define NLAYERS 4

// ---------------- CSR build ----------------

// count degrees; rank[e] = arrival order among edges with same dst
__global__ void count_edges_k(const int* __restrict__ ei, int E,
                              int* __restrict__ cnt_row, int* __restrict__ cnt_col,
                              int* __restrict__ rank) {
    int e = blockIdx.x * blockDim.x + threadIdx.x;
    if (e >= E) return;
    int r = ei[e];
    int c = ei[E + e];
    atomicAdd(&cnt_row[r], 1);              // no-return: out-degree (gamma denom)
    rank[e] = atomicAdd(&cnt_col[c], 1);    // in-degree + slot rank
}

__global__ void dinv_k(const int* __restrict__ cnt_col, float* __restrict__ dinv, int n) {
    int v = blockIdx.x * blockDim.x + threadIdx.x;
    if (v >= n) return;
    dinv[v] = 1.0f / sqrtf((float)(cnt_col[v] + 1));   // deg incl. self loop
}

// block-level exclusive scan (1024 elems / block), emits block sums
__global__ void scanA_k(const int* __restrict__ cnt, int* __restrict__ off,
                        int* __restrict__ bsum, int n) {
    __shared__ int t[1024];
    int i = blockIdx.x * 1024 + threadIdx.x;
    int x = (i < n) ? cnt[i] : 0;
    t[threadIdx.x] = x;
    __syncthreads();
    for (int d = 1; d < 1024; d <<= 1) {
        int y = (threadIdx.x >= (unsigned)d) ? t[threadIdx.x - d] : 0;
        __syncthreads();
        t[threadIdx.x] += y;
        __syncthreads();
    }
    if (i < n) off[i] = t[threadIdx.x] - x;   // exclusive
    if (threadIdx.x == 1023) bsum[blockIdx.x] = t[1023];
}

__global__ void scanB_k(int* __restrict__ bsum, int nb) {
    __shared__ int t[1024];
    int x = (threadIdx.x < (unsigned)nb) ? bsum[threadIdx.x] : 0;
    t[threadIdx.x] = x;
    __syncthreads();
    for (int d = 1; d < 1024; d <<= 1) {
        int y = (threadIdx.x >= (unsigned)d) ? t[threadIdx.x - d] : 0;
        __syncthreads();
        t[threadIdx.x] += y;
        __syncthreads();
    }
    if (threadIdx.x < (unsigned)nb) bsum[threadIdx.x] = t[threadIdx.x] - x;
}

__global__ void scanC_k(int* __restrict__ off, const int* __restrict__ bsum, int n, int total) {
    int i = blockIdx.x * 1024 + threadIdx.x;
    if (i < n) off[i] += bsum[blockIdx.x];
    if (i == 0) off[n] = total;
}

// atomic-free fill: slot = col_off[c] + rank[e]
__global__ void fill_k(const int* __restrict__ ei, int E, const float* __restrict__ dinv,
                       const int* __restrict__ col_off, const int* __restrict__ rank,
                       uint2* __restrict__ csr) {
    int e = blockIdx.x * blockDim.x + threadIdx.x;
    if (e >= E) return;
    int r = ei[e];
    int c = ei[E + e];
    uint2 ent;
    ent.x = (unsigned)r;
    ent.y = __float_as_uint(dinv[r]);
    csr[col_off[c] + rank[e]] = ent;
}

// ---------------- dense (row-major A [n,K] @ W[M,K]^T + b) ----------------

template<int K, int M, bool RELU, bool BIAS>
__global__ void dense_k(const float* __restrict__ A, const float* __restrict__ W,
                        const float* __restrict__ b, float* __restrict__ out, int n) {
    int v = blockIdx.x * blockDim.x + threadIdx.x;
    if (v >= n) return;
    float a[K];
    const float4* ap = reinterpret_cast<const float4*>(A + (size_t)v * K);
#pragma unroll
    for (int k = 0; k < K / 4; ++k) {
        float4 t = ap[k];
        a[4 * k + 0] = t.x; a[4 * k + 1] = t.y; a[4 * k + 2] = t.z; a[4 * k + 3] = t.w;
    }
    float4* op = reinterpret_cast<float4*>(out + (size_t)v * M);
#pragma unroll 1
    for (int m = 0; m < M; m += 4) {
        float acc0 = BIAS ? b[m + 0] : 0.f;
        float acc1 = BIAS ? b[m + 1] : 0.f;
        float acc2 = BIAS ? b[m + 2] : 0.f;
        float acc3 = BIAS ? b[m + 3] : 0.f;
#pragma unroll
        for (int k = 0; k < K; ++k) {
            float av = a[k];
            acc0 = fmaf(av, W[(m + 0) * K + k], acc0);
            acc1 = fmaf(av, W[(m + 1) * K + k], acc1);
            acc2 = fmaf(av, W[(m + 2) * K + k], acc2);
            acc3 = fmaf(av, W[(m + 3) * K + k], acc3);
        }
        if (RELU) {
            acc0 = fmaxf(acc0, 0.f); acc1 = fmaxf(acc1, 0.f);
            acc2 = fmaxf(acc2, 0.f); acc3 = fmaxf(acc3, 0.f);
        }
        float4 o; o.x = acc0; o.y = acc1; o.z = acc2; o.w = acc3;
        op[m >> 2] = o;
    }
}

// ---------------- fused gather: agg (in-edges of v) + gamma scatter ----------------
// wave per node; 4 groups of 16 lanes; each group handles every 4th in-edge,
// loading one full X row as float4/lane. Computes:
//   pre[v] = dinv[v] * sum_in(dinv[src] * X[src]) + dinv[v]^2 * X[v]
//   gs[src] += ||X[src] - X[v]||^2  (no-return float atomic; edge (src->v))
__global__ void gather_k(const float* __restrict__ X, const uint2* __restrict__ csr,
                         const int* __restrict__ col_off, const float* __restrict__ dinv,
                         float* __restrict__ pre, float* __restrict__ gs, int n) {
    int v = blockIdx.x * 4 + (threadIdx.x >> 6);
    if (v >= n) return;
    int lane = threadIdx.x & 63;
    int grp = lane >> 4;
    int sub = lane & 15;

    float4 xv = reinterpret_cast<const float4*>(X + (size_t)v * NHID)[sub];
    int beg = col_off[v], end = col_off[v + 1];

    float4 acc = make_float4(0.f, 0.f, 0.f, 0.f);
    for (int e = beg + grp; e < end; e += 4) {
        uint2 ent = csr[e];
        float4 xs = reinterpret_cast<const float4*>(X + (size_t)ent.x * NHID)[sub];
        float w = __uint_as_float(ent.y);
        acc.x = fmaf(w, xs.x, acc.x);
        acc.y = fmaf(w, xs.y, acc.y);
        acc.z = fmaf(w, xs.z, acc.z);
        acc.w = fmaf(w, xs.w, acc.w);
        float dx = xs.x - xv.x;
        float part = dx * dx;
        dx = xs.y - xv.y; part = fmaf(dx, dx, part);
        dx = xs.z - xv.z; part = fmaf(dx, dx, part);
        dx = xs.w - xv.w; part = fmaf(dx, dx, part);
#pragma unroll
        for (int m = 1; m <= 8; m <<= 1) part += __shfl_xor(part, m, 64);
        if (sub == 0) atomicAdd(&gs[ent.x], part);
    }
    // reduce acc across the 4 groups
#pragma unroll
    for (int m = 16; m <= 32; m <<= 1) {
        acc.x += __shfl_xor(acc.x, m, 64);
        acc.y += __shfl_xor(acc.y, m, 64);
        acc.z += __shfl_xor(acc.z, m, 64);
        acc.w += __shfl_xor(acc.w, m, 64);
    }
    if (grp == 0) {
        float dv = dinv[v];
        float dv2 = dv * dv;
        float4 o;
        o.x = fmaf(dv, acc.x, dv2 * xv.x);
        o.y = fmaf(dv, acc.y, dv2 * xv.y);
        o.z = fmaf(dv, acc.z, dv2 * xv.z);
        o.w = fmaf(dv, acc.w, dv2 * xv.w);
        reinterpret_cast<float4*>(pre + (size_t)v * NHID)[sub] = o;
    }
}

// ---------------- fused per-layer epilogue ----------------
// t = relu(pre @ W^T + b); g = tanh(gs/max(outdeg,1));
// X = (X + g*(t + skip)) / (1 + 2g);  gs = 0 for next layer
__global__ void update_k(float* __restrict__ X, const float* __restrict__ pre,
                         const float* __restrict__ skip, const float* __restrict__ W,
                         const float* __restrict__ b, float* __restrict__ gs,
                         const int* __restrict__ cnt_row, int n) {
    int v = blockIdx.x * blockDim.x + threadIdx.x;
    if (v >= n) return;
    float a[NHID];
    const float4* ap = reinterpret_cast<const float4*>(pre + (size_t)v * NHID);
#pragma unroll
    for (int k = 0; k < NHID / 4; ++k) {
        float4 t = ap[k];
        a[4 * k + 0] = t.x; a[4 * k + 1] = t.y; a[4 * k + 2] = t.z; a[4 * k + 3] = t.w;
    }
    float gv = tanhf(gs[v] / fmaxf((float)cnt_row[v], 1.f));
    gs[v] = 0.f;
    float inv = 1.0f / (1.0f + 2.0f * gv);

    float4* Xp = reinterpret_cast<float4*>(X + (size_t)v * NHID);
    const float4* Sp = reinterpret_cast<const float4*>(skip + (size_t)v * NHID);
#pragma unroll 1
    for (int m = 0; m < NHID; m += 4) {
        float t0 = b[m + 0], t1 = b[m + 1], t2 = b[m + 2], t3 = b[m + 3];
#pragma unroll
        for (int k = 0; k < NHID; ++k) {
            float av = a[k];
            t0 = fmaf(av, W[(m + 0) * NHID + k], t0);
            t1 = fmaf(av, W[(m + 1) * NHID + k], t1);
            t2 = fmaf(av, W[(m + 2) * NHID + k], t2);
            t3 = fmaf(av, W[(m + 3) * NHID + k], t3);
        }
        t0 = fmaxf(t0, 0.f); t1 = fmaxf(t1, 0.f);
        t2 = fmaxf(t2, 0.f); t3 = fmaxf(t3, 0.f);
        float4 x4 = Xp[m >> 2];
        float4 s4 = Sp[m >> 2];
        float4 o;
        o.x = (x4.x + gv * (t0 + s4.x)) * inv;
        o.y = (x4.y + gv * (t1 + s4.y)) * inv;
        o.z = (x4.z + gv * (t2 + s4.z)) * inv;
        o.w = (x4.w + gv * (t3 + s4.w)) * inv;
        Xp[m >> 2] = o;
    }
}

// ---------------- launch ----------------

extern "C" void kernel_launch(void* const* d_in, const int* in_sizes, int n_in,
                              void* d_out, int out_size, void* d_ws, size_t ws_size,
                              hipStream_t stream) {
    const float* x      = (const float*)d_in[0];
    const int*   ei     = (const int*)  d_in[1];
    const float* enc_W  = (const float*)d_in[2];
    const float* enc_b  = (const float*)d_in[3];
    const float* conv_W = (const float*)d_in[4];
    const float* conv_b = (const float*)d_in[5];
    const float* W_skip = (const float*)d_in[6];
    const float* dec_W  = (const float*)d_in[7];
    const float* dec_b  = (const float*)d_in[8];

    const int n = in_sizes[0] / NFEAT;
    const int E = in_sizes[1] / 2;

    char* ws = (char*)d_ws;
    auto alloc = [&](size_t bytes) {
        char* p = ws;
        ws += (bytes + 255) & ~(size_t)255;
        return p;
    };

    float* X    = (float*)alloc((size_t)n * NHID * 4);
    float* pre  = (float*)alloc((size_t)n * NHID * 4);
    float* skip = (float*)alloc((size_t)n * NHID * 4);
    float* gs   = (float*)alloc((size_t)n * 4);
    float* dinv = (float*)alloc((size_t)n * 4);
    int* cnt_row = (int*)alloc((size_t)n * 4);
    int* cnt_col = (int*)alloc((size_t)n * 4);
    int* col_off = (int*)alloc((size_t)(n + 1) * 4);
    int* rank    = (int*)alloc((size_t)E * 4);
    int* bsc     = (int*)alloc(1024 * 4);
    uint2* csr   = (uint2*)alloc((size_t)E * 8);

    hipMemsetAsync(cnt_row, 0, (size_t)n * 4, stream);
    hipMemsetAsync(cnt_col, 0, (size_t)n * 4, stream);
    hipMemsetAsync(gs, 0, (size_t)n * 4, stream);

    count_edges_k<<<(E + 255) / 256, 256, 0, stream>>>(ei, E, cnt_row, cnt_col, rank);
    dinv_k<<<(n + 255) / 256, 256, 0, stream>>>(cnt_col, dinv, n);

    int nb = (n + 1023) / 1024;
    scanA_k<<<nb, 1024, 0, stream>>>(cnt_col, col_off, bsc, n);
    scanB_k<<<1, 1024, 0, stream>>>(bsc, nb);
    scanC_k<<<nb, 1024, 0, stream>>>(col_off, bsc, n, E);
    fill_k<<<(E + 255) / 256, 256, 0, stream>>>(ei, E, dinv, col_off, rank, csr);

    // encoder: X = relu(x @ enc_W^T + enc_b)
    dense_k<NFEAT, NHID, true, true><<<(n + 255) / 256, 256, 0, stream>>>(x, enc_W, enc_b, X, n);
    // skip_val = X_init @ W_skip^T
    dense_k<NHID, NHID, false, false><<<(n + 255) / 256, 256, 0, stream>>>(X, W_skip, nullptr, skip, n);

    for (int l = 0; l < NLAYERS; ++l) {
        gather_k<<<(n + 3) / 4, 256, 0, stream>>>(X, csr, col_off, dinv, pre, gs, n);
        update_k<<<(n + 255) / 256, 256, 0, stream>>>(X, pre, skip, conv_W, conv_b, gs, cnt_row, n);
    }

    // decode: out = X @ dec_W^T + dec_b
    dense_k<NHID, NCLASS, false, true><<<(n + 255) / 256, 256, 0, stream>>>(X, dec_W, dec_b, (float*)d_out, n);
}